// Round 15
// baseline (484.638 us; speedup 1.0000x reference)
//
#include <hip/hip_runtime.h>

#define N_NODES 100000
#define N_EDGES 3200000
#define N_FEAT 24
#define PADF4 8                         // padded row = 32 floats = 128B (one fetch line)
#define BSHIFT 7                        // 128 rows per bucket
#define BROWS 128
#define NBUCK ((N_NODES + BROWS - 1) >> BSHIFT)   // 782
#define PTHREADS 768                    // part block size (12 waves)
#define EPT 8                           // edges per thread in partition
#define TILE (PTHREADS * EPT)           // 6144 edges per block-tile
#define NTILES ((N_EDGES + TILE - 1) / TILE)      // 521
#define CAP 4352                        // place stage entries (34KB), mean+4sd + guard
#define DMAX 256                        // degree buckets for balance sort
#define NKEY (BROWS * 16)               // 2048: (row_local 7b) x (colbin 4b)

// ---------------- wave-parallel scans ----------------
__device__ __forceinline__ int wave_incl_scan(int v, int lane) {
    #pragma unroll
    for (int off = 1; off < 64; off <<= 1) {
        int n = __shfl_up(v, off, 64);
        if (lane >= off) v += n;
    }
    return v;
}
// exclusive prefix across 256 threads; wsum = int[4] LDS scratch
__device__ __forceinline__ int block_excl_scan256(int v, int tid, int* wsum) {
    int lane = tid & 63, wid = tid >> 6;
    int inc = wave_incl_scan(v, lane);
    if (lane == 63) wsum[wid] = inc;
    __syncthreads();
    int base = 0;
    #pragma unroll
    for (int w = 0; w < 3; ++w) base += (w < wid) ? wsum[w] : 0;
    return base + inc - v;
}
// exclusive prefix across 768 threads; wsum = int[12] LDS scratch
__device__ __forceinline__ int block_excl_scan768(int v, int tid, int* wsum) {
    int lane = tid & 63, wid = tid >> 6;
    int inc = wave_incl_scan(v, lane);
    if (lane == 63) wsum[wid] = inc;
    __syncthreads();
    int base = 0;
    #pragma unroll
    for (int w = 0; w < 11; ++w) base += (w < wid) ? wsum[w] : 0;
    return base + inc - v;
}

// ---------------- bucket histogram (LDS-aggregated, int4 reads) ----------------
__global__ __launch_bounds__(256) void bhist_kernel(const int4* __restrict__ row4,
                                                    int* __restrict__ bcnt) {
    __shared__ int h[NBUCK];
    for (int i = threadIdx.x; i < NBUCK; i += 256) h[i] = 0;
    __syncthreads();
    int stride = gridDim.x * blockDim.x;
    const int n4 = N_EDGES / 4;   // 800000, exact
    for (int i = blockIdx.x * blockDim.x + threadIdx.x; i < n4; i += stride) {
        int4 r = row4[i];
        atomicAdd(&h[r.x >> BSHIFT], 1);
        atomicAdd(&h[r.y >> BSHIFT], 1);
        atomicAdd(&h[r.z >> BSHIFT], 1);
        atomicAdd(&h[r.w >> BSHIFT], 1);
    }
    __syncthreads();
    for (int i = threadIdx.x; i < NBUCK; i += 256) {
        int c = h[i];
        if (c) atomicAdd(&bcnt[i], c);
    }
}

// ---------------- bucket exclusive scan -> bbase[0..NBUCK], bcursor ----------------
__global__ __launch_bounds__(1024) void bscan_kernel(const int* __restrict__ bcnt,
                                                     int* __restrict__ bbase,
                                                     int* __restrict__ bcursor) {
    __shared__ int part[1024];
    int tid = threadIdx.x;
    int v = (tid < NBUCK) ? bcnt[tid] : 0;
    part[tid] = v;
    __syncthreads();
    for (int off = 1; off < 1024; off <<= 1) {
        int p = (tid >= off) ? part[tid - off] : 0;
        __syncthreads();
        part[tid] += p;
        __syncthreads();
    }
    int ex = (tid > 0) ? part[tid - 1] : 0;
    if (tid <= NBUCK) {
        bbase[tid] = ex;              // bbase[NBUCK] == N_EDGES
        if (tid < NBUCK) bcursor[tid] = ex;
    }
}

// ---------------- level 1: partition (768 threads, EPT=8, TILE=6144) ----------------
__global__ __launch_bounds__(PTHREADS) void part_kernel(const int* __restrict__ row,
                                                        const int* __restrict__ col,
                                                        const float* __restrict__ val,
                                                        int* __restrict__ bcursor,
                                                        int2* __restrict__ epk) {
    __shared__ int h[NBUCK];
    __shared__ int lstart[NBUCK];
    __shared__ int delta[NBUCK];      // gpos[b] - lstart[b]
    __shared__ int wsum[12];
    __shared__ int2 stage[TILE];      // 48 KB
    __shared__ unsigned short bidx[TILE];  // 12 KB
    const int tid = threadIdx.x;
    for (int i = tid; i < NBUCK; i += PTHREADS) h[i] = 0;
    __syncthreads();

    const int tbase = blockIdx.x * TILE;
    const int m = min(TILE, N_EDGES - tbase);
    const int base = tbase + tid * EPT;
    int rowj[EPT], rk[EPT];
    #pragma unroll
    for (int j = 0; j < EPT; ++j) {
        int e = base + j;
        if (e < N_EDGES) {
            int r = row[e];
            rowj[j] = r;
            rk[j] = atomicAdd(&h[r >> BSHIFT], 1);
        } else rowj[j] = -1;
    }
    __syncthreads();

    {   // exclusive scan h -> lstart (chunk=2 per thread, wave-parallel)
        int lo = tid * 2;
        int hi = min(NBUCK, lo + 2);
        int s = 0;
        for (int j = lo; j < hi; ++j) s += h[j];
        int run = block_excl_scan768(s, tid, wsum);
        for (int j = lo; j < hi; ++j) {
            lstart[j] = run;
            run += h[j];
        }
    }
    __syncthreads();

    // reserve global chunks (one atomic per (block,bucket))
    for (int i = tid; i < NBUCK; i += PTHREADS) {
        int c = h[i];
        int g = c ? atomicAdd(&bcursor[i], c) : 0;
        delta[i] = g - lstart[i];
    }
    __syncthreads();

    #pragma unroll
    for (int j = 0; j < EPT; ++j) {
        if (rowj[j] >= 0) {
            int e = base + j;
            int b = rowj[j] >> BSHIFT;
            int rl = rowj[j] & (BROWS - 1);
            int slot = lstart[b] + rk[j];
            int2 pk;
            pk.x = col[e] | (rl << 17);   // col < 2^17, rl < 2^7
            pk.y = __float_as_int(val[e]);
            stage[slot] = pk;
            bidx[slot] = (unsigned short)b;
        }
    }
    __syncthreads();

    for (int i = tid; i < m; i += PTHREADS) {
        int b = bidx[i];
        epk[delta[b] + i] = stage[i];
    }
}

// ---------------- level 2: CSR placement, column-sorted within each row ----------------
// key = (row_local << 4) | (col >> 13). Emits starts[] + degree histogram.
__global__ __launch_bounds__(256) void place_kernel(const int* __restrict__ bbase,
                                                    int2* __restrict__ epk,
                                                    int* __restrict__ starts,
                                                    int* __restrict__ dcnt) {
    __shared__ int kcnt[NKEY];       // 8 KB
    __shared__ int kcur[NKEY];       // 8 KB
    __shared__ int wsum[4];
    __shared__ int dh[DMAX];
    __shared__ int2 stage[CAP];      // 34 KB
    int b = blockIdx.x;
    int tid = threadIdx.x;
    int gb = bbase[b];
    int n = bbase[b + 1] - gb;
    for (int j = tid; j < NKEY; j += 256) kcnt[j] = 0;
    dh[tid] = 0;
    __syncthreads();
    for (int i = tid; i < n; i += 256) {
        int x = epk[gb + i].x;
        int key = (((x >> 17) & (BROWS - 1)) << 4) | ((x >> 13) & 15);
        atomicAdd(&kcnt[key], 1);
    }
    __syncthreads();
    // thread tid (< BROWS) owns row tid's 16 bins
    int deg = 0;
    if (tid < BROWS) {
        int lo = tid << 4;
        #pragma unroll
        for (int j = 0; j < 16; ++j) deg += kcnt[lo + j];
    }
    int r_glob = (b << BSHIFT) + tid;
    if (tid < BROWS && r_glob < N_NODES) atomicAdd(&dh[min(deg, DMAX - 1)], 1);
    int run = block_excl_scan256(deg, tid, wsum);
    if (tid < BROWS && r_glob < N_NODES) starts[r_glob] = gb + run;
    if (b == 0 && tid == 0) starts[N_NODES] = N_EDGES;
    if (tid < BROWS) {
        int lo = tid << 4;
        #pragma unroll
        for (int j = 0; j < 16; ++j) {
            kcur[lo + j] = run;
            run += kcnt[lo + j];
        }
    }
    __syncthreads();
    {   // flush degree histogram
        int c = dh[tid];
        if (c) atomicAdd(&dcnt[tid], c);
    }
    for (int i = tid; i < n; i += 256) {
        int2 p = epk[gb + i];
        int key = (((p.x >> 17) & (BROWS - 1)) << 4) | ((p.x >> 13) & 15);
        int slot = atomicAdd(&kcur[key], 1);
        int2 fin;
        fin.x = p.x & 0x1FFFF;       // strip row_local
        fin.y = p.y;
        if (slot < CAP) stage[slot] = fin;
        else epk[gb + slot] = fin;   // rare overflow: direct write (deterministic)
    }
    __syncthreads();
    for (int i = tid; i < n && i < CAP; i += 256) epk[gb + i] = stage[i];
}

// ---------------- degree scan (DESCENDING: LPT) + counting-sort scatter ----------------
__global__ __launch_bounds__(256) void dscan_kernel(const int* __restrict__ dcnt,
                                                    int* __restrict__ dcur) {
    __shared__ int part[DMAX];
    int tid = threadIdx.x;
    int v = dcnt[tid];
    part[tid] = v;
    __syncthreads();
    for (int off = 1; off < DMAX; off <<= 1) {
        int p = (tid >= off) ? part[tid - off] : 0;
        __syncthreads();
        part[tid] += p;
        __syncthreads();
    }
    // descending layout: rows with degree > tid come first
    dcur[tid] = N_NODES - part[tid];
}

__global__ __launch_bounds__(256) void dscatter_kernel(const int* __restrict__ starts,
                                                       int* __restrict__ dcur,
                                                       int* __restrict__ perm) {
    __shared__ int h[DMAX];
    __shared__ int chunk[DMAX];
    int tid = threadIdx.x;
    int r = blockIdx.x * 256 + tid;
    h[tid] = 0;
    __syncthreads();
    int d = -1, rk = 0;
    if (r < N_NODES) {
        d = min(starts[r + 1] - starts[r], DMAX - 1);
        rk = atomicAdd(&h[d], 1);
    }
    __syncthreads();
    int c = h[tid];
    chunk[tid] = c ? atomicAdd(&dcur[tid], c) : 0;   // one atomic per (block,deg)
    __syncthreads();
    if (r < N_NODES) perm[chunk[d] + rk] = r;
}

// ---------------- pad-copy: x [N][24] -> bufA [N][32] ----------------
__global__ __launch_bounds__(256) void pad_copy_kernel(const float4* __restrict__ x4,
                                                       float4* __restrict__ dst) {
    int t = blockIdx.x * blockDim.x + threadIdx.x;
    int r = t >> 3;
    if (r >= N_NODES) return;
    int sub = t & 7;
    float4 v;
    if (sub < 6) v = x4[r * 6 + sub];
    else         v = make_float4(0.f, 0.f, 0.f, 0.f);
    dst[r * PADF4 + sub] = v;
}

// ---------------- SpMM: 8 lanes/row, 1 float4/lane, 4-edge unroll ----------------
// epk is a pure stream (zero reuse) -> non-temporal loads keep it from
// evicting the src gather window in L2.
#define ACC4(v, xv, a)                                       \
    a.x = fmaf(v, xv.x, a.x); a.y = fmaf(v, xv.y, a.y);      \
    a.z = fmaf(v, xv.z, a.z); a.w = fmaf(v, xv.w, a.w);

__device__ __forceinline__ int2 nt_load_e(const int2* p) {
    long long v = __builtin_nontemporal_load((const long long*)p);
    int2 r;
    r.x = (int)(v & 0xFFFFFFFFll);
    r.y = (int)(v >> 32);
    return r;
}

__global__ __launch_bounds__(256) void spmm_pad_kernel(const int* __restrict__ starts,
                                                       const int* __restrict__ perm,
                                                       const int2* __restrict__ epk,
                                                       const float4* __restrict__ src,
                                                       float4* __restrict__ dst) {
    int t = blockIdx.x * blockDim.x + threadIdx.x;
    int g = t >> 3;
    if (g >= N_NODES) return;
    int rowi = perm[g];
    int sub = t & 7;
    int s = starts[rowi];
    int e = starts[rowi + 1];
    const float4* sp = src + sub;
    float4 acc = make_float4(0.f, 0.f, 0.f, 0.f);
    int i = s;
    for (; i + 3 < e; i += 4) {
        int2 p0 = nt_load_e(&epk[i]);
        int2 p1 = nt_load_e(&epk[i + 1]);
        int2 p2 = nt_load_e(&epk[i + 2]);
        int2 p3 = nt_load_e(&epk[i + 3]);
        float4 x0 = sp[p0.x * PADF4];
        float4 x1 = sp[p1.x * PADF4];
        float4 x2 = sp[p2.x * PADF4];
        float4 x3 = sp[p3.x * PADF4];
        ACC4(__int_as_float(p0.y), x0, acc);
        ACC4(__int_as_float(p1.y), x1, acc);
        ACC4(__int_as_float(p2.y), x2, acc);
        ACC4(__int_as_float(p3.y), x3, acc);
    }
    for (; i < e; ++i) {
        int2 p = epk[i];
        float4 xv = sp[p.x * PADF4];
        ACC4(__int_as_float(p.y), xv, acc);
    }
    dst[rowi * PADF4 + sub] = acc;
}

__global__ __launch_bounds__(256) void spmm_final_kernel(const int* __restrict__ starts,
                                                         const int* __restrict__ perm,
                                                         const int2* __restrict__ epk,
                                                         const float4* __restrict__ src,
                                                         float* __restrict__ out) {
    int t = blockIdx.x * blockDim.x + threadIdx.x;
    int g = t >> 3;
    if (g >= N_NODES) return;
    int rowi = perm[g];
    int sub = t & 7;
    int s = starts[rowi];
    int e = starts[rowi + 1];
    const float4* sp = src + sub;
    float4 acc = make_float4(0.f, 0.f, 0.f, 0.f);
    int i = s;
    for (; i + 3 < e; i += 4) {
        int2 p0 = nt_load_e(&epk[i]);
        int2 p1 = nt_load_e(&epk[i + 1]);
        int2 p2 = nt_load_e(&epk[i + 2]);
        int2 p3 = nt_load_e(&epk[i + 3]);
        float4 x0 = sp[p0.x * PADF4];
        float4 x1 = sp[p1.x * PADF4];
        float4 x2 = sp[p2.x * PADF4];
        float4 x3 = sp[p3.x * PADF4];
        ACC4(__int_as_float(p0.y), x0, acc);
        ACC4(__int_as_float(p1.y), x1, acc);
        ACC4(__int_as_float(p2.y), x2, acc);
        ACC4(__int_as_float(p3.y), x3, acc);
    }
    for (; i < e; ++i) {
        int2 p = epk[i];
        float4 xv = sp[p.x * PADF4];
        ACC4(__int_as_float(p.y), xv, acc);
    }
    if (sub < 6) *(float4*)(out + rowi * N_FEAT + sub * 4) = acc;
}

// ---------------- launch ----------------

extern "C" void kernel_launch(void* const* d_in, const int* in_sizes, int n_in,
                              void* d_out, int out_size, void* d_ws, size_t ws_size,
                              hipStream_t stream) {
    const float* x       = (const float*)d_in[0];
    const float* values  = (const float*)d_in[1];
    const int*   row_idx = (const int*)d_in[2];
    const int*   col_idx = (const int*)d_in[3];
    float* out = (float*)d_out;

    char* ws = (char*)d_ws;
    // workspace layout (~52MB, 128B-aligned offsets)
    int*    bcnt    = (int*)(ws + 0);          // NBUCK ints
    int*    bbase   = (int*)(ws + 4096);       // NBUCK+1 ints
    int*    bcursor = (int*)(ws + 8192);       // NBUCK ints
    int*    dcnt    = (int*)(ws + 12288);      // DMAX ints
    int*    dcur    = (int*)(ws + 16384);      // DMAX ints
    int*    starts  = (int*)(ws + 20480);      // N_NODES+1 ints
    int*    perm    = (int*)(ws + 420608);     // N_NODES ints
    int2*   epk     = (int2*)(ws + 820736);    // E * 8B = 25.6 MB
    float4* bufA    = (float4*)(ws + 26420864);// N*32 floats = 12.8 MB
    float4* bufB    = (float4*)(ws + 39220864);// N*32 floats = 12.8 MB

    hipMemsetAsync(bcnt, 0, NBUCK * sizeof(int), stream);
    hipMemsetAsync(dcnt, 0, DMAX * sizeof(int), stream);
    bhist_kernel<<<512, 256, 0, stream>>>((const int4*)row_idx, bcnt);
    bscan_kernel<<<1, 1024, 0, stream>>>(bcnt, bbase, bcursor);
    part_kernel<<<NTILES, PTHREADS, 0, stream>>>(row_idx, col_idx, values, bcursor, epk);
    place_kernel<<<NBUCK, 256, 0, stream>>>(bbase, epk, starts, dcnt);

    const int node_blocks = (N_NODES + 255) / 256;
    dscan_kernel<<<1, DMAX, 0, stream>>>(dcnt, dcur);
    dscatter_kernel<<<node_blocks, 256, 0, stream>>>(starts, dcur, perm);

    const int spmm_blocks = (N_NODES * 8 + 255) / 256;
    pad_copy_kernel<<<spmm_blocks, 256, 0, stream>>>((const float4*)x, bufA);
    spmm_pad_kernel<<<spmm_blocks, 256, 0, stream>>>(starts, perm, epk, bufA, bufB);
    spmm_pad_kernel<<<spmm_blocks, 256, 0, stream>>>(starts, perm, epk, bufB, bufA);
    spmm_pad_kernel<<<spmm_blocks, 256, 0, stream>>>(starts, perm, epk, bufA, bufB);
    spmm_pad_kernel<<<spmm_blocks, 256, 0, stream>>>(starts, perm, epk, bufB, bufA);
    spmm_pad_kernel<<<spmm_blocks, 256, 0, stream>>>(starts, perm, epk, bufA, bufB);
    spmm_final_kernel<<<spmm_blocks, 256, 0, stream>>>(starts, perm, epk, bufB, out);
}

// Round 16
// 407.045 us; speedup vs baseline: 1.1906x; 1.1906x over previous
//
#include <hip/hip_runtime.h>

#define N_NODES 100000
#define N_EDGES 3200000
#define N_FEAT 24
#define PADF4 8                         // padded row = 32 floats = 128B (one fetch line)
#define BSHIFT 7                        // 128 rows per bucket
#define BROWS 128
#define NBUCK ((N_NODES + BROWS - 1) >> BSHIFT)   // 782
#define PTHREADS 768                    // part block size (12 waves)
#define EPT 8                           // edges per thread in partition
#define TILE (PTHREADS * EPT)           // 6144 edges per block-tile
#define NTILES ((N_EDGES + TILE - 1) / TILE)      // 521
#define CAP 4352                        // place stage entries (34KB), mean+4sd + guard
#define DMAX 256                        // degree buckets for balance sort
#define NKEY (BROWS * 16)               // 2048: (row_local 7b) x (colbin 4b)

// ---------------- wave-parallel scans ----------------
__device__ __forceinline__ int wave_incl_scan(int v, int lane) {
    #pragma unroll
    for (int off = 1; off < 64; off <<= 1) {
        int n = __shfl_up(v, off, 64);
        if (lane >= off) v += n;
    }
    return v;
}
// exclusive prefix across 256 threads; wsum = int[4] LDS scratch
__device__ __forceinline__ int block_excl_scan256(int v, int tid, int* wsum) {
    int lane = tid & 63, wid = tid >> 6;
    int inc = wave_incl_scan(v, lane);
    if (lane == 63) wsum[wid] = inc;
    __syncthreads();
    int base = 0;
    #pragma unroll
    for (int w = 0; w < 3; ++w) base += (w < wid) ? wsum[w] : 0;
    return base + inc - v;
}
// exclusive prefix across 768 threads; wsum = int[12] LDS scratch
__device__ __forceinline__ int block_excl_scan768(int v, int tid, int* wsum) {
    int lane = tid & 63, wid = tid >> 6;
    int inc = wave_incl_scan(v, lane);
    if (lane == 63) wsum[wid] = inc;
    __syncthreads();
    int base = 0;
    #pragma unroll
    for (int w = 0; w < 11; ++w) base += (w < wid) ? wsum[w] : 0;
    return base + inc - v;
}

// ---------------- bucket histogram (LDS-aggregated, int4 reads) ----------------
__global__ __launch_bounds__(256) void bhist_kernel(const int4* __restrict__ row4,
                                                    int* __restrict__ bcnt) {
    __shared__ int h[NBUCK];
    for (int i = threadIdx.x; i < NBUCK; i += 256) h[i] = 0;
    __syncthreads();
    int stride = gridDim.x * blockDim.x;
    const int n4 = N_EDGES / 4;   // 800000, exact
    for (int i = blockIdx.x * blockDim.x + threadIdx.x; i < n4; i += stride) {
        int4 r = row4[i];
        atomicAdd(&h[r.x >> BSHIFT], 1);
        atomicAdd(&h[r.y >> BSHIFT], 1);
        atomicAdd(&h[r.z >> BSHIFT], 1);
        atomicAdd(&h[r.w >> BSHIFT], 1);
    }
    __syncthreads();
    for (int i = threadIdx.x; i < NBUCK; i += 256) {
        int c = h[i];
        if (c) atomicAdd(&bcnt[i], c);
    }
}

// ---------------- bucket exclusive scan -> bbase[0..NBUCK], bcursor ----------------
__global__ __launch_bounds__(1024) void bscan_kernel(const int* __restrict__ bcnt,
                                                     int* __restrict__ bbase,
                                                     int* __restrict__ bcursor) {
    __shared__ int part[1024];
    int tid = threadIdx.x;
    int v = (tid < NBUCK) ? bcnt[tid] : 0;
    part[tid] = v;
    __syncthreads();
    for (int off = 1; off < 1024; off <<= 1) {
        int p = (tid >= off) ? part[tid - off] : 0;
        __syncthreads();
        part[tid] += p;
        __syncthreads();
    }
    int ex = (tid > 0) ? part[tid - 1] : 0;
    if (tid <= NBUCK) {
        bbase[tid] = ex;              // bbase[NBUCK] == N_EDGES
        if (tid < NBUCK) bcursor[tid] = ex;
    }
}

// ---------------- level 1: partition (768 threads, EPT=8, TILE=6144) ----------------
__global__ __launch_bounds__(PTHREADS) void part_kernel(const int* __restrict__ row,
                                                        const int* __restrict__ col,
                                                        const float* __restrict__ val,
                                                        int* __restrict__ bcursor,
                                                        int2* __restrict__ epk) {
    __shared__ int h[NBUCK];
    __shared__ int lstart[NBUCK];
    __shared__ int delta[NBUCK];      // gpos[b] - lstart[b]
    __shared__ int wsum[12];
    __shared__ int2 stage[TILE];      // 48 KB
    __shared__ unsigned short bidx[TILE];  // 12 KB
    const int tid = threadIdx.x;
    for (int i = tid; i < NBUCK; i += PTHREADS) h[i] = 0;
    __syncthreads();

    const int tbase = blockIdx.x * TILE;
    const int m = min(TILE, N_EDGES - tbase);
    const int base = tbase + tid * EPT;
    int rowj[EPT], rk[EPT];
    #pragma unroll
    for (int j = 0; j < EPT; ++j) {
        int e = base + j;
        if (e < N_EDGES) {
            int r = row[e];
            rowj[j] = r;
            rk[j] = atomicAdd(&h[r >> BSHIFT], 1);
        } else rowj[j] = -1;
    }
    __syncthreads();

    {   // exclusive scan h -> lstart (chunk=2 per thread, wave-parallel)
        int lo = tid * 2;
        int hi = min(NBUCK, lo + 2);
        int s = 0;
        for (int j = lo; j < hi; ++j) s += h[j];
        int run = block_excl_scan768(s, tid, wsum);
        for (int j = lo; j < hi; ++j) {
            lstart[j] = run;
            run += h[j];
        }
    }
    __syncthreads();

    // reserve global chunks (one atomic per (block,bucket))
    for (int i = tid; i < NBUCK; i += PTHREADS) {
        int c = h[i];
        int g = c ? atomicAdd(&bcursor[i], c) : 0;
        delta[i] = g - lstart[i];
    }
    __syncthreads();

    #pragma unroll
    for (int j = 0; j < EPT; ++j) {
        if (rowj[j] >= 0) {
            int e = base + j;
            int b = rowj[j] >> BSHIFT;
            int rl = rowj[j] & (BROWS - 1);
            int slot = lstart[b] + rk[j];
            int2 pk;
            pk.x = col[e] | (rl << 17);   // col < 2^17, rl < 2^7
            pk.y = __float_as_int(val[e]);
            stage[slot] = pk;
            bidx[slot] = (unsigned short)b;
        }
    }
    __syncthreads();

    for (int i = tid; i < m; i += PTHREADS) {
        int b = bidx[i];
        epk[delta[b] + i] = stage[i];
    }
}

// ---------------- level 2: CSR placement, column-sorted within each row ----------------
// key = (row_local << 4) | (col >> 13). Emits starts[] + degree histogram.
__global__ __launch_bounds__(256) void place_kernel(const int* __restrict__ bbase,
                                                    int2* __restrict__ epk,
                                                    int* __restrict__ starts,
                                                    int* __restrict__ dcnt) {
    __shared__ int kcnt[NKEY];       // 8 KB
    __shared__ int kcur[NKEY];       // 8 KB
    __shared__ int wsum[4];
    __shared__ int dh[DMAX];
    __shared__ int2 stage[CAP];      // 34 KB
    int b = blockIdx.x;
    int tid = threadIdx.x;
    int gb = bbase[b];
    int n = bbase[b + 1] - gb;
    for (int j = tid; j < NKEY; j += 256) kcnt[j] = 0;
    dh[tid] = 0;
    __syncthreads();
    for (int i = tid; i < n; i += 256) {
        int x = epk[gb + i].x;
        int key = (((x >> 17) & (BROWS - 1)) << 4) | ((x >> 13) & 15);
        atomicAdd(&kcnt[key], 1);
    }
    __syncthreads();
    // thread tid (< BROWS) owns row tid's 16 bins
    int deg = 0;
    if (tid < BROWS) {
        int lo = tid << 4;
        #pragma unroll
        for (int j = 0; j < 16; ++j) deg += kcnt[lo + j];
    }
    int r_glob = (b << BSHIFT) + tid;
    if (tid < BROWS && r_glob < N_NODES) atomicAdd(&dh[min(deg, DMAX - 1)], 1);
    int run = block_excl_scan256(deg, tid, wsum);
    if (tid < BROWS && r_glob < N_NODES) starts[r_glob] = gb + run;
    if (b == 0 && tid == 0) starts[N_NODES] = N_EDGES;
    if (tid < BROWS) {
        int lo = tid << 4;
        #pragma unroll
        for (int j = 0; j < 16; ++j) {
            kcur[lo + j] = run;
            run += kcnt[lo + j];
        }
    }
    __syncthreads();
    {   // flush degree histogram
        int c = dh[tid];
        if (c) atomicAdd(&dcnt[tid], c);
    }
    for (int i = tid; i < n; i += 256) {
        int2 p = epk[gb + i];
        int key = (((p.x >> 17) & (BROWS - 1)) << 4) | ((p.x >> 13) & 15);
        int slot = atomicAdd(&kcur[key], 1);
        int2 fin;
        fin.x = p.x & 0x1FFFF;       // strip row_local
        fin.y = p.y;
        if (slot < CAP) stage[slot] = fin;
        else epk[gb + slot] = fin;   // rare overflow: direct write (deterministic)
    }
    __syncthreads();
    for (int i = tid; i < n && i < CAP; i += 256) epk[gb + i] = stage[i];
}

// ---------------- degree scan (DESCENDING: LPT) + counting-sort scatter ----------------
__global__ __launch_bounds__(256) void dscan_kernel(const int* __restrict__ dcnt,
                                                    int* __restrict__ dcur) {
    __shared__ int part[DMAX];
    int tid = threadIdx.x;
    int v = dcnt[tid];
    part[tid] = v;
    __syncthreads();
    for (int off = 1; off < DMAX; off <<= 1) {
        int p = (tid >= off) ? part[tid - off] : 0;
        __syncthreads();
        part[tid] += p;
        __syncthreads();
    }
    // descending layout: rows with degree > tid come first
    dcur[tid] = N_NODES - part[tid];
}

__global__ __launch_bounds__(256) void dscatter_kernel(const int* __restrict__ starts,
                                                       int* __restrict__ dcur,
                                                       int* __restrict__ perm) {
    __shared__ int h[DMAX];
    __shared__ int chunk[DMAX];
    int tid = threadIdx.x;
    int r = blockIdx.x * 256 + tid;
    h[tid] = 0;
    __syncthreads();
    int d = -1, rk = 0;
    if (r < N_NODES) {
        d = min(starts[r + 1] - starts[r], DMAX - 1);
        rk = atomicAdd(&h[d], 1);
    }
    __syncthreads();
    int c = h[tid];
    chunk[tid] = c ? atomicAdd(&dcur[tid], c) : 0;   // one atomic per (block,deg)
    __syncthreads();
    if (r < N_NODES) perm[chunk[d] + rk] = r;
}

// ---------------- pad-copy: x [N][24] -> bufA [N][32] ----------------
__global__ __launch_bounds__(256) void pad_copy_kernel(const float4* __restrict__ x4,
                                                       float4* __restrict__ dst) {
    int t = blockIdx.x * blockDim.x + threadIdx.x;
    int r = t >> 3;
    if (r >= N_NODES) return;
    int sub = t & 7;
    float4 v;
    if (sub < 6) v = x4[r * 6 + sub];
    else         v = make_float4(0.f, 0.f, 0.f, 0.f);
    dst[r * PADF4 + sub] = v;
}

// ---------------- SpMM: 8 lanes/row, 1 float4/lane, 4-edge unroll ----------------
// Plain (cached) epk loads: epk lines are broadcast across the 8-lane group
// and shared across iterations -- R15's nontemporal hint cost +54MB FETCH.
#define ACC4(v, xv, a)                                       \
    a.x = fmaf(v, xv.x, a.x); a.y = fmaf(v, xv.y, a.y);      \
    a.z = fmaf(v, xv.z, a.z); a.w = fmaf(v, xv.w, a.w);

__global__ __launch_bounds__(256) void spmm_pad_kernel(const int* __restrict__ starts,
                                                       const int* __restrict__ perm,
                                                       const int2* __restrict__ epk,
                                                       const float4* __restrict__ src,
                                                       float4* __restrict__ dst) {
    int t = blockIdx.x * blockDim.x + threadIdx.x;
    int g = t >> 3;
    if (g >= N_NODES) return;
    int rowi = perm[g];
    int sub = t & 7;
    int s = starts[rowi];
    int e = starts[rowi + 1];
    const float4* sp = src + sub;
    float4 acc = make_float4(0.f, 0.f, 0.f, 0.f);
    int i = s;
    for (; i + 3 < e; i += 4) {
        int2 p0 = epk[i];
        int2 p1 = epk[i + 1];
        int2 p2 = epk[i + 2];
        int2 p3 = epk[i + 3];
        float4 x0 = sp[p0.x * PADF4];
        float4 x1 = sp[p1.x * PADF4];
        float4 x2 = sp[p2.x * PADF4];
        float4 x3 = sp[p3.x * PADF4];
        ACC4(__int_as_float(p0.y), x0, acc);
        ACC4(__int_as_float(p1.y), x1, acc);
        ACC4(__int_as_float(p2.y), x2, acc);
        ACC4(__int_as_float(p3.y), x3, acc);
    }
    for (; i < e; ++i) {
        int2 p = epk[i];
        float4 xv = sp[p.x * PADF4];
        ACC4(__int_as_float(p.y), xv, acc);
    }
    dst[rowi * PADF4 + sub] = acc;
}

__global__ __launch_bounds__(256) void spmm_final_kernel(const int* __restrict__ starts,
                                                         const int* __restrict__ perm,
                                                         const int2* __restrict__ epk,
                                                         const float4* __restrict__ src,
                                                         float* __restrict__ out) {
    int t = blockIdx.x * blockDim.x + threadIdx.x;
    int g = t >> 3;
    if (g >= N_NODES) return;
    int rowi = perm[g];
    int sub = t & 7;
    int s = starts[rowi];
    int e = starts[rowi + 1];
    const float4* sp = src + sub;
    float4 acc = make_float4(0.f, 0.f, 0.f, 0.f);
    int i = s;
    for (; i + 3 < e; i += 4) {
        int2 p0 = epk[i];
        int2 p1 = epk[i + 1];
        int2 p2 = epk[i + 2];
        int2 p3 = epk[i + 3];
        float4 x0 = sp[p0.x * PADF4];
        float4 x1 = sp[p1.x * PADF4];
        float4 x2 = sp[p2.x * PADF4];
        float4 x3 = sp[p3.x * PADF4];
        ACC4(__int_as_float(p0.y), x0, acc);
        ACC4(__int_as_float(p1.y), x1, acc);
        ACC4(__int_as_float(p2.y), x2, acc);
        ACC4(__int_as_float(p3.y), x3, acc);
    }
    for (; i < e; ++i) {
        int2 p = epk[i];
        float4 xv = sp[p.x * PADF4];
        ACC4(__int_as_float(p.y), xv, acc);
    }
    if (sub < 6) *(float4*)(out + rowi * N_FEAT + sub * 4) = acc;
}

// ---------------- launch ----------------

extern "C" void kernel_launch(void* const* d_in, const int* in_sizes, int n_in,
                              void* d_out, int out_size, void* d_ws, size_t ws_size,
                              hipStream_t stream) {
    const float* x       = (const float*)d_in[0];
    const float* values  = (const float*)d_in[1];
    const int*   row_idx = (const int*)d_in[2];
    const int*   col_idx = (const int*)d_in[3];
    float* out = (float*)d_out;

    char* ws = (char*)d_ws;
    // workspace layout (~52MB, 128B-aligned offsets)
    int*    bcnt    = (int*)(ws + 0);          // NBUCK ints
    int*    bbase   = (int*)(ws + 4096);       // NBUCK+1 ints
    int*    bcursor = (int*)(ws + 8192);       // NBUCK ints
    int*    dcnt    = (int*)(ws + 12288);      // DMAX ints
    int*    dcur    = (int*)(ws + 16384);      // DMAX ints
    int*    starts  = (int*)(ws + 20480);      // N_NODES+1 ints
    int*    perm    = (int*)(ws + 420608);     // N_NODES ints
    int2*   epk     = (int2*)(ws + 820736);    // E * 8B = 25.6 MB
    float4* bufA    = (float4*)(ws + 26420864);// N*32 floats = 12.8 MB
    float4* bufB    = (float4*)(ws + 39220864);// N*32 floats = 12.8 MB

    hipMemsetAsync(bcnt, 0, NBUCK * sizeof(int), stream);
    hipMemsetAsync(dcnt, 0, DMAX * sizeof(int), stream);
    bhist_kernel<<<512, 256, 0, stream>>>((const int4*)row_idx, bcnt);
    bscan_kernel<<<1, 1024, 0, stream>>>(bcnt, bbase, bcursor);
    part_kernel<<<NTILES, PTHREADS, 0, stream>>>(row_idx, col_idx, values, bcursor, epk);
    place_kernel<<<NBUCK, 256, 0, stream>>>(bbase, epk, starts, dcnt);

    const int node_blocks = (N_NODES + 255) / 256;
    dscan_kernel<<<1, DMAX, 0, stream>>>(dcnt, dcur);
    dscatter_kernel<<<node_blocks, 256, 0, stream>>>(starts, dcur, perm);

    const int spmm_blocks = (N_NODES * 8 + 255) / 256;
    pad_copy_kernel<<<spmm_blocks, 256, 0, stream>>>((const float4*)x, bufA);
    spmm_pad_kernel<<<spmm_blocks, 256, 0, stream>>>(starts, perm, epk, bufA, bufB);
    spmm_pad_kernel<<<spmm_blocks, 256, 0, stream>>>(starts, perm, epk, bufB, bufA);
    spmm_pad_kernel<<<spmm_blocks, 256, 0, stream>>>(starts, perm, epk, bufA, bufB);
    spmm_pad_kernel<<<spmm_blocks, 256, 0, stream>>>(starts, perm, epk, bufB, bufA);
    spmm_pad_kernel<<<spmm_blocks, 256, 0, stream>>>(starts, perm, epk, bufA, bufB);
    spmm_final_kernel<<<spmm_blocks, 256, 0, stream>>>(starts, perm, epk, bufB, out);
}

// Round 17
// 390.019 us; speedup vs baseline: 1.2426x; 1.0437x over previous
//
#include <hip/hip_runtime.h>

#define N_NODES 100000
#define N_EDGES 3200000
#define N_FEAT 24
#define PADF4 8                         // padded row = 32 floats = 128B (one fetch line)
#define BSHIFT 7                        // 128 rows per bucket
#define BROWS 128
#define NBUCK ((N_NODES + BROWS - 1) >> BSHIFT)   // 782
#define PTHREADS 768                    // part block size (12 waves)
#define EPT 8                           // edges per thread in partition
#define TILE (PTHREADS * EPT)           // 6144 edges per block-tile
#define NTILES ((N_EDGES + TILE - 1) / TILE)      // 521
#define CAP 4352                        // place stage entries (34KB), mean+4sd + guard
#define DMAX 256                        // degree buckets for balance sort
#define NKEY (BROWS * 16)               // 2048: (row_local 7b) x (colbin 4b)
#define SPMM_LDS_CAP 33792              // 33KB dummy dynamic LDS: caps spmm at 4 blocks/CU

// ---------------- wave-parallel scans ----------------
__device__ __forceinline__ int wave_incl_scan(int v, int lane) {
    #pragma unroll
    for (int off = 1; off < 64; off <<= 1) {
        int n = __shfl_up(v, off, 64);
        if (lane >= off) v += n;
    }
    return v;
}
// exclusive prefix across 256 threads; wsum = int[4] LDS scratch
__device__ __forceinline__ int block_excl_scan256(int v, int tid, int* wsum) {
    int lane = tid & 63, wid = tid >> 6;
    int inc = wave_incl_scan(v, lane);
    if (lane == 63) wsum[wid] = inc;
    __syncthreads();
    int base = 0;
    #pragma unroll
    for (int w = 0; w < 3; ++w) base += (w < wid) ? wsum[w] : 0;
    return base + inc - v;
}
// exclusive prefix across 768 threads; wsum = int[12] LDS scratch
__device__ __forceinline__ int block_excl_scan768(int v, int tid, int* wsum) {
    int lane = tid & 63, wid = tid >> 6;
    int inc = wave_incl_scan(v, lane);
    if (lane == 63) wsum[wid] = inc;
    __syncthreads();
    int base = 0;
    #pragma unroll
    for (int w = 0; w < 11; ++w) base += (w < wid) ? wsum[w] : 0;
    return base + inc - v;
}

// ---------------- bucket histogram (LDS-aggregated, int4 reads) ----------------
__global__ __launch_bounds__(256) void bhist_kernel(const int4* __restrict__ row4,
                                                    int* __restrict__ bcnt) {
    __shared__ int h[NBUCK];
    for (int i = threadIdx.x; i < NBUCK; i += 256) h[i] = 0;
    __syncthreads();
    int stride = gridDim.x * blockDim.x;
    const int n4 = N_EDGES / 4;   // 800000, exact
    for (int i = blockIdx.x * blockDim.x + threadIdx.x; i < n4; i += stride) {
        int4 r = row4[i];
        atomicAdd(&h[r.x >> BSHIFT], 1);
        atomicAdd(&h[r.y >> BSHIFT], 1);
        atomicAdd(&h[r.z >> BSHIFT], 1);
        atomicAdd(&h[r.w >> BSHIFT], 1);
    }
    __syncthreads();
    for (int i = threadIdx.x; i < NBUCK; i += 256) {
        int c = h[i];
        if (c) atomicAdd(&bcnt[i], c);
    }
}

// ---------------- bucket exclusive scan -> bbase[0..NBUCK], bcursor ----------------
__global__ __launch_bounds__(1024) void bscan_kernel(const int* __restrict__ bcnt,
                                                     int* __restrict__ bbase,
                                                     int* __restrict__ bcursor) {
    __shared__ int part[1024];
    int tid = threadIdx.x;
    int v = (tid < NBUCK) ? bcnt[tid] : 0;
    part[tid] = v;
    __syncthreads();
    for (int off = 1; off < 1024; off <<= 1) {
        int p = (tid >= off) ? part[tid - off] : 0;
        __syncthreads();
        part[tid] += p;
        __syncthreads();
    }
    int ex = (tid > 0) ? part[tid - 1] : 0;
    if (tid <= NBUCK) {
        bbase[tid] = ex;              // bbase[NBUCK] == N_EDGES
        if (tid < NBUCK) bcursor[tid] = ex;
    }
}

// ---------------- level 1: partition (768 threads, EPT=8, TILE=6144) ----------------
__global__ __launch_bounds__(PTHREADS) void part_kernel(const int* __restrict__ row,
                                                        const int* __restrict__ col,
                                                        const float* __restrict__ val,
                                                        int* __restrict__ bcursor,
                                                        int2* __restrict__ epk) {
    __shared__ int h[NBUCK];
    __shared__ int lstart[NBUCK];
    __shared__ int delta[NBUCK];      // gpos[b] - lstart[b]
    __shared__ int wsum[12];
    __shared__ int2 stage[TILE];      // 48 KB
    __shared__ unsigned short bidx[TILE];  // 12 KB
    const int tid = threadIdx.x;
    for (int i = tid; i < NBUCK; i += PTHREADS) h[i] = 0;
    __syncthreads();

    const int tbase = blockIdx.x * TILE;
    const int m = min(TILE, N_EDGES - tbase);
    const int base = tbase + tid * EPT;
    int rowj[EPT], rk[EPT];
    #pragma unroll
    for (int j = 0; j < EPT; ++j) {
        int e = base + j;
        if (e < N_EDGES) {
            int r = row[e];
            rowj[j] = r;
            rk[j] = atomicAdd(&h[r >> BSHIFT], 1);
        } else rowj[j] = -1;
    }
    __syncthreads();

    {   // exclusive scan h -> lstart (chunk=2 per thread, wave-parallel)
        int lo = tid * 2;
        int hi = min(NBUCK, lo + 2);
        int s = 0;
        for (int j = lo; j < hi; ++j) s += h[j];
        int run = block_excl_scan768(s, tid, wsum);
        for (int j = lo; j < hi; ++j) {
            lstart[j] = run;
            run += h[j];
        }
    }
    __syncthreads();

    // reserve global chunks (one atomic per (block,bucket))
    for (int i = tid; i < NBUCK; i += PTHREADS) {
        int c = h[i];
        int g = c ? atomicAdd(&bcursor[i], c) : 0;
        delta[i] = g - lstart[i];
    }
    __syncthreads();

    #pragma unroll
    for (int j = 0; j < EPT; ++j) {
        if (rowj[j] >= 0) {
            int e = base + j;
            int b = rowj[j] >> BSHIFT;
            int rl = rowj[j] & (BROWS - 1);
            int slot = lstart[b] + rk[j];
            int2 pk;
            pk.x = col[e] | (rl << 17);   // col < 2^17, rl < 2^7
            pk.y = __float_as_int(val[e]);
            stage[slot] = pk;
            bidx[slot] = (unsigned short)b;
        }
    }
    __syncthreads();

    for (int i = tid; i < m; i += PTHREADS) {
        int b = bidx[i];
        epk[delta[b] + i] = stage[i];
    }
}

// ---------------- level 2: CSR placement, column-sorted within each row ----------------
// key = (row_local << 4) | (col >> 13). Emits starts[] + degree histogram.
__global__ __launch_bounds__(256) void place_kernel(const int* __restrict__ bbase,
                                                    int2* __restrict__ epk,
                                                    int* __restrict__ starts,
                                                    int* __restrict__ dcnt) {
    __shared__ int kcnt[NKEY];       // 8 KB
    __shared__ int kcur[NKEY];       // 8 KB
    __shared__ int wsum[4];
    __shared__ int dh[DMAX];
    __shared__ int2 stage[CAP];      // 34 KB
    int b = blockIdx.x;
    int tid = threadIdx.x;
    int gb = bbase[b];
    int n = bbase[b + 1] - gb;
    for (int j = tid; j < NKEY; j += 256) kcnt[j] = 0;
    dh[tid] = 0;
    __syncthreads();
    for (int i = tid; i < n; i += 256) {
        int x = epk[gb + i].x;
        int key = (((x >> 17) & (BROWS - 1)) << 4) | ((x >> 13) & 15);
        atomicAdd(&kcnt[key], 1);
    }
    __syncthreads();
    // thread tid (< BROWS) owns row tid's 16 bins
    int deg = 0;
    if (tid < BROWS) {
        int lo = tid << 4;
        #pragma unroll
        for (int j = 0; j < 16; ++j) deg += kcnt[lo + j];
    }
    int r_glob = (b << BSHIFT) + tid;
    if (tid < BROWS && r_glob < N_NODES) atomicAdd(&dh[min(deg, DMAX - 1)], 1);
    int run = block_excl_scan256(deg, tid, wsum);
    if (tid < BROWS && r_glob < N_NODES) starts[r_glob] = gb + run;
    if (b == 0 && tid == 0) starts[N_NODES] = N_EDGES;
    if (tid < BROWS) {
        int lo = tid << 4;
        #pragma unroll
        for (int j = 0; j < 16; ++j) {
            kcur[lo + j] = run;
            run += kcnt[lo + j];
        }
    }
    __syncthreads();
    {   // flush degree histogram
        int c = dh[tid];
        if (c) atomicAdd(&dcnt[tid], c);
    }
    for (int i = tid; i < n; i += 256) {
        int2 p = epk[gb + i];
        int key = (((p.x >> 17) & (BROWS - 1)) << 4) | ((p.x >> 13) & 15);
        int slot = atomicAdd(&kcur[key], 1);
        int2 fin;
        fin.x = p.x & 0x1FFFF;       // strip row_local
        fin.y = p.y;
        if (slot < CAP) stage[slot] = fin;
        else epk[gb + slot] = fin;   // rare overflow: direct write (deterministic)
    }
    __syncthreads();
    for (int i = tid; i < n && i < CAP; i += 256) epk[gb + i] = stage[i];
}

// ---------------- degree scan (DESCENDING: LPT) + counting-sort scatter ----------------
__global__ __launch_bounds__(256) void dscan_kernel(const int* __restrict__ dcnt,
                                                    int* __restrict__ dcur) {
    __shared__ int part[DMAX];
    int tid = threadIdx.x;
    int v = dcnt[tid];
    part[tid] = v;
    __syncthreads();
    for (int off = 1; off < DMAX; off <<= 1) {
        int p = (tid >= off) ? part[tid - off] : 0;
        __syncthreads();
        part[tid] += p;
        __syncthreads();
    }
    // descending layout: rows with degree > tid come first
    dcur[tid] = N_NODES - part[tid];
}

__global__ __launch_bounds__(256) void dscatter_kernel(const int* __restrict__ starts,
                                                       int* __restrict__ dcur,
                                                       int* __restrict__ perm) {
    __shared__ int h[DMAX];
    __shared__ int chunk[DMAX];
    int tid = threadIdx.x;
    int r = blockIdx.x * 256 + tid;
    h[tid] = 0;
    __syncthreads();
    int d = -1, rk = 0;
    if (r < N_NODES) {
        d = min(starts[r + 1] - starts[r], DMAX - 1);
        rk = atomicAdd(&h[d], 1);
    }
    __syncthreads();
    int c = h[tid];
    chunk[tid] = c ? atomicAdd(&dcur[tid], c) : 0;   // one atomic per (block,deg)
    __syncthreads();
    if (r < N_NODES) perm[chunk[d] + rk] = r;
}

// ---------------- pad-copy: x [N][24] -> bufA [N][32] ----------------
__global__ __launch_bounds__(256) void pad_copy_kernel(const float4* __restrict__ x4,
                                                       float4* __restrict__ dst) {
    int t = blockIdx.x * blockDim.x + threadIdx.x;
    int r = t >> 3;
    if (r >= N_NODES) return;
    int sub = t & 7;
    float4 v;
    if (sub < 6) v = x4[r * 6 + sub];
    else         v = make_float4(0.f, 0.f, 0.f, 0.f);
    dst[r * PADF4 + sub] = v;
}

// ---------------- SpMM: 8 lanes/row, 1 float4/lane, 4-edge unroll ----------------
// Launched with 33KB dynamic LDS (unused) to cap residency at 4 blocks/CU:
// narrows the concurrent-row degree band -> tighter chip-wide column window
// -> higher L2 hit rate, while 4-deep ILP preserves MLP.
#define ACC4(v, xv, a)                                       \
    a.x = fmaf(v, xv.x, a.x); a.y = fmaf(v, xv.y, a.y);      \
    a.z = fmaf(v, xv.z, a.z); a.w = fmaf(v, xv.w, a.w);

__global__ __launch_bounds__(256) void spmm_pad_kernel(const int* __restrict__ starts,
                                                       const int* __restrict__ perm,
                                                       const int2* __restrict__ epk,
                                                       const float4* __restrict__ src,
                                                       float4* __restrict__ dst) {
    int t = blockIdx.x * blockDim.x + threadIdx.x;
    int g = t >> 3;
    if (g >= N_NODES) return;
    int rowi = perm[g];
    int sub = t & 7;
    int s = starts[rowi];
    int e = starts[rowi + 1];
    const float4* sp = src + sub;
    float4 acc = make_float4(0.f, 0.f, 0.f, 0.f);
    int i = s;
    for (; i + 3 < e; i += 4) {
        int2 p0 = epk[i];
        int2 p1 = epk[i + 1];
        int2 p2 = epk[i + 2];
        int2 p3 = epk[i + 3];
        float4 x0 = sp[p0.x * PADF4];
        float4 x1 = sp[p1.x * PADF4];
        float4 x2 = sp[p2.x * PADF4];
        float4 x3 = sp[p3.x * PADF4];
        ACC4(__int_as_float(p0.y), x0, acc);
        ACC4(__int_as_float(p1.y), x1, acc);
        ACC4(__int_as_float(p2.y), x2, acc);
        ACC4(__int_as_float(p3.y), x3, acc);
    }
    for (; i < e; ++i) {
        int2 p = epk[i];
        float4 xv = sp[p.x * PADF4];
        ACC4(__int_as_float(p.y), xv, acc);
    }
    dst[rowi * PADF4 + sub] = acc;
}

__global__ __launch_bounds__(256) void spmm_final_kernel(const int* __restrict__ starts,
                                                         const int* __restrict__ perm,
                                                         const int2* __restrict__ epk,
                                                         const float4* __restrict__ src,
                                                         float* __restrict__ out) {
    int t = blockIdx.x * blockDim.x + threadIdx.x;
    int g = t >> 3;
    if (g >= N_NODES) return;
    int rowi = perm[g];
    int sub = t & 7;
    int s = starts[rowi];
    int e = starts[rowi + 1];
    const float4* sp = src + sub;
    float4 acc = make_float4(0.f, 0.f, 0.f, 0.f);
    int i = s;
    for (; i + 3 < e; i += 4) {
        int2 p0 = epk[i];
        int2 p1 = epk[i + 1];
        int2 p2 = epk[i + 2];
        int2 p3 = epk[i + 3];
        float4 x0 = sp[p0.x * PADF4];
        float4 x1 = sp[p1.x * PADF4];
        float4 x2 = sp[p2.x * PADF4];
        float4 x3 = sp[p3.x * PADF4];
        ACC4(__int_as_float(p0.y), x0, acc);
        ACC4(__int_as_float(p1.y), x1, acc);
        ACC4(__int_as_float(p2.y), x2, acc);
        ACC4(__int_as_float(p3.y), x3, acc);
    }
    for (; i < e; ++i) {
        int2 p = epk[i];
        float4 xv = sp[p.x * PADF4];
        ACC4(__int_as_float(p.y), xv, acc);
    }
    if (sub < 6) *(float4*)(out + rowi * N_FEAT + sub * 4) = acc;
}

// ---------------- launch ----------------

extern "C" void kernel_launch(void* const* d_in, const int* in_sizes, int n_in,
                              void* d_out, int out_size, void* d_ws, size_t ws_size,
                              hipStream_t stream) {
    const float* x       = (const float*)d_in[0];
    const float* values  = (const float*)d_in[1];
    const int*   row_idx = (const int*)d_in[2];
    const int*   col_idx = (const int*)d_in[3];
    float* out = (float*)d_out;

    char* ws = (char*)d_ws;
    // workspace layout (~52MB, 128B-aligned offsets)
    int*    bcnt    = (int*)(ws + 0);          // NBUCK ints
    int*    bbase   = (int*)(ws + 4096);       // NBUCK+1 ints
    int*    bcursor = (int*)(ws + 8192);       // NBUCK ints
    int*    dcnt    = (int*)(ws + 12288);      // DMAX ints
    int*    dcur    = (int*)(ws + 16384);      // DMAX ints
    int*    starts  = (int*)(ws + 20480);      // N_NODES+1 ints
    int*    perm    = (int*)(ws + 420608);     // N_NODES ints
    int2*   epk     = (int2*)(ws + 820736);    // E * 8B = 25.6 MB
    float4* bufA    = (float4*)(ws + 26420864);// N*32 floats = 12.8 MB
    float4* bufB    = (float4*)(ws + 39220864);// N*32 floats = 12.8 MB

    hipMemsetAsync(bcnt, 0, NBUCK * sizeof(int), stream);
    hipMemsetAsync(dcnt, 0, DMAX * sizeof(int), stream);
    bhist_kernel<<<512, 256, 0, stream>>>((const int4*)row_idx, bcnt);
    bscan_kernel<<<1, 1024, 0, stream>>>(bcnt, bbase, bcursor);
    part_kernel<<<NTILES, PTHREADS, 0, stream>>>(row_idx, col_idx, values, bcursor, epk);
    place_kernel<<<NBUCK, 256, 0, stream>>>(bbase, epk, starts, dcnt);

    const int node_blocks = (N_NODES + 255) / 256;
    dscan_kernel<<<1, DMAX, 0, stream>>>(dcnt, dcur);
    dscatter_kernel<<<node_blocks, 256, 0, stream>>>(starts, dcur, perm);

    const int spmm_blocks = (N_NODES * 8 + 255) / 256;
    pad_copy_kernel<<<spmm_blocks, 256, 0, stream>>>((const float4*)x, bufA);
    spmm_pad_kernel<<<spmm_blocks, 256, SPMM_LDS_CAP, stream>>>(starts, perm, epk, bufA, bufB);
    spmm_pad_kernel<<<spmm_blocks, 256, SPMM_LDS_CAP, stream>>>(starts, perm, epk, bufB, bufA);
    spmm_pad_kernel<<<spmm_blocks, 256, SPMM_LDS_CAP, stream>>>(starts, perm, epk, bufA, bufB);
    spmm_pad_kernel<<<spmm_blocks, 256, SPMM_LDS_CAP, stream>>>(starts, perm, epk, bufB, bufA);
    spmm_pad_kernel<<<spmm_blocks, 256, SPMM_LDS_CAP, stream>>>(starts, perm, epk, bufA, bufB);
    spmm_final_kernel<<<spmm_blocks, 256, SPMM_LDS_CAP, stream>>>(starts, perm, epk, bufB, out);
}